// Round 20
// baseline (213.398 us; speedup 1.0000x reference)
//
#include <hip/hip_runtime.h>
#include <math.h>

#define F_IN 256
#define HDIM 128
#define NCLS 20
#define NEG_SLOPE 0.2f
#define SCAN_CHUNK 1024

typedef float f32x4 __attribute__((ext_vector_type(4)));
typedef _Float16 f16x2 __attribute__((ext_vector_type(2)));
typedef _Float16 f16x4 __attribute__((ext_vector_type(4)));
typedef _Float16 f16x8 __attribute__((ext_vector_type(8)));

static __device__ __forceinline__ float lrelu(float x) { return x > 0.f ? x : NEG_SLOPE * x; }

// ---------------- fast zero ----------------
__global__ __launch_bounds__(256) void zero_kernel(int4* __restrict__ p, int n4) {
    int i = blockIdx.x * blockDim.x + threadIdx.x;
    if (i < n4) p[i] = make_int4(0, 0, 0, 0);
}

// ---------------- CSR build ----------------
__global__ void count_kernel(const int* __restrict__ ei, int E, int N, int* __restrict__ deg) {
    int e = blockIdx.x * blockDim.x + threadIdx.x;
    int Etot = E + N;
    if (e >= Etot) return;
    int d = (e < E) ? ei[E + e] : (e - E);
    atomicAdd(&deg[d], 1);
}

__global__ __launch_bounds__(256) void scan_reduce_kernel(const int* __restrict__ deg, int n,
                                                          int* __restrict__ bsums) {
    int base = blockIdx.x * SCAN_CHUNK + threadIdx.x * 4;
    int s = 0;
    if (base + 3 < n) {
        int4 v = *reinterpret_cast<const int4*>(&deg[base]);
        s = v.x + v.y + v.z + v.w;
    } else {
#pragma unroll
        for (int j = 0; j < 4; ++j) if (base + j < n) s += deg[base + j];
    }
#pragma unroll
    for (int o = 32; o > 0; o >>= 1) s += __shfl_down(s, o);
    __shared__ int ws[4];
    int lane = threadIdx.x & 63, w = threadIdx.x >> 6;
    if (lane == 0) ws[w] = s;
    __syncthreads();
    if (threadIdx.x == 0) bsums[blockIdx.x] = ws[0] + ws[1] + ws[2] + ws[3];
}

__global__ __launch_bounds__(256) void scan_bsums_kernel(int* __restrict__ bsums, int nb,
                                                         int* __restrict__ off, int n) {
    __shared__ int sh[256];
    int tid = threadIdx.x;
    int v = (tid < nb) ? bsums[tid] : 0;
    sh[tid] = v;
    __syncthreads();
    for (int d = 1; d < 256; d <<= 1) {
        int t = (tid >= d) ? sh[tid - d] : 0;
        __syncthreads();
        sh[tid] += t;
        __syncthreads();
    }
    if (tid < nb) bsums[tid] = sh[tid] - v;
    if (tid == 255) off[n] = sh[255];
}

__global__ __launch_bounds__(256) void scan_down_kernel(const int* __restrict__ deg, int n,
                                                        const int* __restrict__ bpre,
                                                        int* __restrict__ off) {
    int base = blockIdx.x * SCAN_CHUNK + threadIdx.x * 4;
    int v0 = 0, v1 = 0, v2 = 0, v3 = 0;
    if (base + 3 < n) {
        int4 t = *reinterpret_cast<const int4*>(&deg[base]);
        v0 = t.x; v1 = t.y; v2 = t.z; v3 = t.w;
    } else {
        if (base + 0 < n) v0 = deg[base + 0];
        if (base + 1 < n) v1 = deg[base + 1];
        if (base + 2 < n) v2 = deg[base + 2];
        if (base + 3 < n) v3 = deg[base + 3];
    }
    int tsum = v0 + v1 + v2 + v3;
    int lane = threadIdx.x & 63, w = threadIdx.x >> 6;
    int inc = tsum;
#pragma unroll
    for (int o = 1; o < 64; o <<= 1) {
        int t = __shfl_up(inc, o);
        if (lane >= o) inc += t;
    }
    int texc = inc - tsum;
    __shared__ int wsum[4];
    if (lane == 63) wsum[w] = inc;
    __syncthreads();
    int wpre = 0;
    for (int i = 0; i < w; ++i) wpre += wsum[i];
    int p = bpre[blockIdx.x] + wpre + texc;
    if (base + 3 < n) {
        int4 o4;
        o4.x = p; o4.y = p + v0; o4.z = p + v0 + v1; o4.w = p + v0 + v1 + v2;
        *reinterpret_cast<int4*>(&off[base]) = o4;
    } else {
        int run = p;
        if (base + 0 < n) { off[base + 0] = run; run += v0; }
        if (base + 1 < n) { off[base + 1] = run; run += v1; }
        if (base + 2 < n) { off[base + 2] = run; run += v2; }
        if (base + 3 < n) { off[base + 3] = run; }
    }
}

// scatter uses deg as a COUNTDOWN cursor (deg dead after scan).
__global__ void scatter_kernel(const int* __restrict__ ei, int E, int N,
                               const int* __restrict__ off, int* __restrict__ deg,
                               int* __restrict__ csr_src) {
    int e = blockIdx.x * blockDim.x + threadIdx.x;
    int Etot = E + N;
    if (e >= Etot) return;
    int s, d;
    if (e < E) { s = ei[e]; d = ei[E + e]; } else { s = d = e - E; }
    int pos = off[d] + atomicSub(&deg[d], 1) - 1;
    csr_src[pos] = s;
}

// ---------------- pack weights into MFMA B-fragment order (fp16 hi|lo interleaved) ----------------
__global__ __launch_bounds__(64) void pack_b_kernel(const float* __restrict__ W1,
                                                    const float* __restrict__ W2,
                                                    const float* __restrict__ Wm1,
                                                    _Float16* __restrict__ p1,
                                                    _Float16* __restrict__ p2,
                                                    _Float16* __restrict__ p3) {
    int t = blockIdx.x;
    int lane = threadIdx.x;
    const float* B; _Float16* out; int r;
    if (t < 64)      { B = W1;  out = p1; r = t; }
    else if (t < 96) { B = W2;  out = p2; r = t - 64; }
    else             { B = Wm1; out = p3; r = t - 96; }
    int ks = r >> 3, cf = r & 7;
    int c  = cf * 16 + (lane & 15);
    int k0 = ks * 32 + (lane >> 4) * 8;
    size_t base = ((size_t)r * 64 + lane) * 16;
#pragma unroll
    for (int i = 0; i < 8; ++i) {
        float v = B[(size_t)(k0 + i) * 128 + c];
        _Float16 h = (_Float16)v;
        out[base + i]     = h;
        out[base + 8 + i] = (_Float16)(v - (float)h);
    }
}

// ---------------- MFMA GEMM: C[M,128](fp16) = A[M,K] @ Bpacked[K,128] (+bias, act) ----------------
// Block = 32 rows / 2 waves (r19 proven); wave = 32 rows x 64 cols.
// THIS ROUND: whole-K A-panel staged to LDS per block (coalesced reg-staging,
// padded rows -> conflict-free ds_read_b128; both waves share the panel; global
// latency paid ONCE per block instead of per K-step — the one pipeline structure
// the compiler preserves; r17/r18: register-level hoists get undone by regalloc).
// B stays global depth-2 ping-pong (L2-hot). r8: no forced min-occupancy.
// Fused alpha epilogue (a_src != null); fused MLP head (FUSE_HEAD, gemm3 only).
template <int AFMT, int KSTEPS, int FUSE_HEAD>
__global__ __launch_bounds__(128) void gemm_mfma_kernel(
        const void* __restrict__ Aptr, const _Float16* __restrict__ Bp,
        _Float16* __restrict__ C, int M,
        const float* __restrict__ bias, int act,
        const float* __restrict__ a_src, const float* __restrict__ a_dst,
        float* __restrict__ as_out, float* __restrict__ ad_out,
        const float* __restrict__ Wh, const float* __restrict__ bh2,
        float* __restrict__ outp) {
    constexpr int K = KSTEPS * 32;
    constexpr int S32 = 260;   // fp32 LDS row stride (floats): pad 4 -> bank-spread, 16B-mult
    constexpr int S16 = 136;   // fp16 LDS row stride (halves): pad 8 -> bank-spread, 16B-mult
    __shared__ float    As32[AFMT == 0 ? 32 * S32 : 1];
    __shared__ _Float16 As16[AFMT == 1 ? 32 * S16 : 1];
    __shared__ float sal[2][2][32];                                // alpha partials [as/ad][wc][row]
    __shared__ float zs[FUSE_HEAD ? 32 : 1][FUSE_HEAD ? 132 : 1];  // z tile (head)
    __shared__ float Wt[FUSE_HEAD ? 20 : 1][FUSE_HEAD ? 132 : 1];  // Wm2^T (head)
    __shared__ float bb[FUSE_HEAD ? 20 : 1];

    int tid = threadIdx.x;
    int lane = tid & 63;
    int wc = tid >> 6;                 // 0..1 (column half)
    int bm = blockIdx.x * 32;
    int l15 = lane & 15, l4 = lane >> 4;
    int koff = l4 * 8;

    if constexpr (FUSE_HEAD) {
        for (int i = tid; i < HDIM * NCLS; i += 128) Wt[i % NCLS][i / NCLS] = Wh[i];
        if (tid < NCLS) bb[tid] = bh2[tid];
    }

    const float*    A32 = (const float*)Aptr;
    const _Float16* A16 = (const _Float16*)Aptr;

    // ---- stage whole 32xK A-panel to LDS (coalesced; rows >= M clamp to M-1) ----
    if constexpr (AFMT == 0) {
#pragma unroll
        for (int r = 0; r < K / 16; ++r) {            // 512 floats/round
            int F = (r * 128 + tid) * 4;
            int row = F / K, k = F % K;
            int rr = bm + row; if (rr >= M) rr = M - 1;
            float4 v = *reinterpret_cast<const float4*>(&A32[(size_t)rr * K + k]);
            *reinterpret_cast<float4*>(&As32[row * S32 + k]) = v;
        }
    } else {
#pragma unroll
        for (int r = 0; r < K / 32; ++r) {            // 1024 halves/round
            int H = (r * 128 + tid) * 8;
            int row = H / K, k = H % K;
            int rr = bm + row; if (rr >= M) rr = M - 1;
            f16x8 v = *reinterpret_cast<const f16x8*>(&A16[(size_t)rr * K + k]);
            *reinterpret_cast<f16x8*>(&As16[row * S16 + k]) = v;
        }
    }
    __syncthreads();

    f32x4 acc[2][4];
#pragma unroll
    for (int m = 0; m < 2; ++m)
#pragma unroll
        for (int j = 0; j < 4; ++j) acc[m][j] = (f32x4){0.f, 0.f, 0.f, 0.f};

    auto ldsA = [&](int ks, f16x8 a[2]) {
        int kb = ks * 32 + koff;
#pragma unroll
        for (int m = 0; m < 2; ++m) {
            int row = l15 + m * 16;
            if (AFMT == 0) {
                float4 u = *reinterpret_cast<const float4*>(&As32[row * S32 + kb]);
                float4 w = *reinterpret_cast<const float4*>(&As32[row * S32 + kb + 4]);
                f16x8 t;
                t[0] = (_Float16)u.x; t[1] = (_Float16)u.y;
                t[2] = (_Float16)u.z; t[3] = (_Float16)u.w;
                t[4] = (_Float16)w.x; t[5] = (_Float16)w.y;
                t[6] = (_Float16)w.z; t[7] = (_Float16)w.w;
                a[m] = t;
            } else {
                a[m] = *reinterpret_cast<const f16x8*>(&As16[row * S16 + kb]);
            }
        }
    };
    auto loadB = [&](int ks, f16x8 bh[4], f16x8 bl[4]) {
#pragma unroll
        for (int j = 0; j < 4; ++j) {
            int cf = wc * 4 + j;
            const _Float16* p = Bp + (((size_t)ks * 8 + cf) * 64 + lane) * 16;
            bh[j] = *reinterpret_cast<const f16x8*>(p);
            bl[j] = *reinterpret_cast<const f16x8*>(p + 8);
        }
    };

    f16x8 a0[2], a1[2], bh0[4], bh1[4], bl0[4], bl1[4];
    loadB(0, bh0, bl0);
#pragma unroll
    for (int ks = 0; ks < KSTEPS; ks += 2) {
        loadB(ks + 1, bh1, bl1);
        ldsA(ks, a0);
#pragma unroll
        for (int j = 0; j < 4; ++j) {
            acc[0][j] = __builtin_amdgcn_mfma_f32_16x16x32_f16(a0[0], bh0[j], acc[0][j], 0, 0, 0);
            acc[1][j] = __builtin_amdgcn_mfma_f32_16x16x32_f16(a0[1], bh0[j], acc[1][j], 0, 0, 0);
            acc[0][j] = __builtin_amdgcn_mfma_f32_16x16x32_f16(a0[0], bl0[j], acc[0][j], 0, 0, 0);
            acc[1][j] = __builtin_amdgcn_mfma_f32_16x16x32_f16(a0[1], bl0[j], acc[1][j], 0, 0, 0);
        }
        if (ks + 2 < KSTEPS) loadB(ks + 2, bh0, bl0);
        ldsA(ks + 1, a1);
#pragma unroll
        for (int j = 0; j < 4; ++j) {
            acc[0][j] = __builtin_amdgcn_mfma_f32_16x16x32_f16(a1[0], bh1[j], acc[0][j], 0, 0, 0);
            acc[1][j] = __builtin_amdgcn_mfma_f32_16x16x32_f16(a1[1], bh1[j], acc[1][j], 0, 0, 0);
            acc[0][j] = __builtin_amdgcn_mfma_f32_16x16x32_f16(a1[0], bl1[j], acc[0][j], 0, 0, 0);
            acc[1][j] = __builtin_amdgcn_mfma_f32_16x16x32_f16(a1[1], bl1[j], acc[1][j], 0, 0, 0);
        }
    }

    // epilogue: C/zs store (+ fused alpha partials)
    float ps[2][4], pd[2][4];
#pragma unroll
    for (int m = 0; m < 2; ++m)
#pragma unroll
        for (int reg = 0; reg < 4; ++reg) { ps[m][reg] = 0.f; pd[m][reg] = 0.f; }

#pragma unroll
    for (int j = 0; j < 4; ++j) {
        int col = wc * 64 + j * 16 + l15;
        float bi = bias ? bias[col] : 0.f;
        float asc = a_src ? a_src[col] : 0.f;
        float adc = a_src ? a_dst[col] : 0.f;
#pragma unroll
        for (int m = 0; m < 2; ++m) {
#pragma unroll
            for (int reg = 0; reg < 4; ++reg) {
                int rloc = m * 16 + l4 * 4 + reg;
                int rr = bm + rloc;
                float v = acc[m][j][reg] + bi;
                if (act) v = fmaxf(v, 0.f);
                if constexpr (FUSE_HEAD) {
                    zs[rloc][col] = v;
                } else {
                    if (rr < M) C[(size_t)rr * 128 + col] = (_Float16)v;
                }
                ps[m][reg] = fmaf(v, asc, ps[m][reg]);
                pd[m][reg] = fmaf(v, adc, pd[m][reg]);
            }
        }
    }

    if (a_src) {
#pragma unroll
        for (int o = 1; o < 16; o <<= 1) {
#pragma unroll
            for (int m = 0; m < 2; ++m)
#pragma unroll
                for (int reg = 0; reg < 4; ++reg) {
                    ps[m][reg] += __shfl_xor(ps[m][reg], o);
                    pd[m][reg] += __shfl_xor(pd[m][reg], o);
                }
        }
        if (l15 == 0) {
#pragma unroll
            for (int m = 0; m < 2; ++m)
#pragma unroll
                for (int reg = 0; reg < 4; ++reg) {
                    int rloc = m * 16 + l4 * 4 + reg;
                    sal[0][wc][rloc] = ps[m][reg];
                    sal[1][wc][rloc] = pd[m][reg];
                }
        }
        __syncthreads();
        if (tid < 32) {
            int rr = bm + tid;
            if (rr < M) {
                as_out[rr] = sal[0][0][tid] + sal[0][1][tid];
                ad_out[rr] = sal[1][0][tid] + sal[1][1][tid];
            }
        }
    }

    if constexpr (FUSE_HEAD) {
        __syncthreads();
        for (int idx = tid; idx < 32 * NCLS; idx += 128) {
            int r = idx / NCLS, c = idx % NCLS;
            int rr = bm + r;
            if (rr >= M) continue;
            float s = bb[c];
#pragma unroll
            for (int k = 0; k < HDIM; k += 4) {
                float4 z4 = *reinterpret_cast<const float4*>(&zs[r][k]);
                float4 w4 = *reinterpret_cast<const float4*>(&Wt[c][k]);
                s = fmaf(z4.x, w4.x, s);
                s = fmaf(z4.y, w4.y, s);
                s = fmaf(z4.z, w4.z, s);
                s = fmaf(z4.w, w4.w, s);
            }
            outp[(size_t)rr * NCLS + c] = 1.f / (1.f + __expf(-s));
        }
    }
}

// ---------------- attention aggregation: one wave per dst node (fp16 gather) ----------------
// Phase A: 64 edges in parallel -> e, denom; stash (src,e) in LDS.
// Phase B: 4 edges in flight (eslot = lane>>4), l15 owns 8 dims via one f16x8 load.
__global__ __launch_bounds__(256) void aggregate_kernel(const _Float16* __restrict__ h,
                                 const float* __restrict__ asrc, const float* __restrict__ adst,
                                 const int* __restrict__ off, const int* __restrict__ csr_src,
                                 const float* __restrict__ bias,
                                 _Float16* __restrict__ out,
                                 int N, int do_relu) {
    __shared__ float2 sm[4][64];
    int wslot = threadIdx.x >> 6;
    int wave = blockIdx.x * 4 + wslot;
    int lane = threadIdx.x & 63;
    if (wave >= N) return;
    int o0 = off[wave], o1 = off[wave + 1];
    float ad = adst[wave];
    int l15 = lane & 15;
    int eslot = lane >> 4;

    float denom = 0.f;
    float acc[8];
#pragma unroll
    for (int i = 0; i < 8; ++i) acc[i] = 0.f;

    for (int base = o0; base < o1; base += 64) {
        int cnt = o1 - base; if (cnt > 64) cnt = 64;
        float e = 0.f; int s = 0;
        if (lane < cnt) {
            s = csr_src[base + lane];
            e = __expf(lrelu(asrc[s] + ad));
        }
        float t = e;
#pragma unroll
        for (int o = 32; o > 0; o >>= 1) t += __shfl_xor(t, o);
        denom += t;
        sm[wslot][lane] = make_float2(__int_as_float(s), e);
        for (int j = eslot; j < cnt; j += 4) {
            float2 se = sm[wslot][j];
            int s0 = __float_as_int(se.x);
            f16x8 hv = *reinterpret_cast<const f16x8*>(&h[(size_t)s0 * HDIM + 8 * l15]);
#pragma unroll
            for (int i = 0; i < 8; ++i) acc[i] = fmaf(se.y, (float)hv[i], acc[i]);
        }
    }

#pragma unroll
    for (int i = 0; i < 8; ++i) {
        acc[i] += __shfl_xor(acc[i], 16);
        acc[i] += __shfl_xor(acc[i], 32);
    }

    if (lane < 16) {
        float inv = 1.f / denom;
        float4 b0 = *reinterpret_cast<const float4*>(&bias[8 * l15]);
        float4 b1 = *reinterpret_cast<const float4*>(&bias[8 * l15 + 4]);
        float bv[8] = {b0.x, b0.y, b0.z, b0.w, b1.x, b1.y, b1.z, b1.w};
        f16x8 o8;
#pragma unroll
        for (int i = 0; i < 8; ++i) {
            float v = acc[i] * inv + bv[i];
            if (do_relu) v = fmaxf(v, 0.f);
            o8[i] = (_Float16)v;
        }
        *reinterpret_cast<f16x8*>(&out[(size_t)wave * HDIM + 8 * l15]) = o8;
    }
}

extern "C" void kernel_launch(void* const* d_in, const int* in_sizes, int n_in,
                              void* d_out, int out_size, void* d_ws, size_t ws_size,
                              hipStream_t stream) {
    const float* x      = (const float*)d_in[0];
    const int*   ei     = (const int*)d_in[1];
    const float* W1     = (const float*)d_in[2];
    const float* a_src1 = (const float*)d_in[3];
    const float* a_dst1 = (const float*)d_in[4];
    const float* b1     = (const float*)d_in[5];
    const float* W2     = (const float*)d_in[6];
    const float* a_src2 = (const float*)d_in[7];
    const float* a_dst2 = (const float*)d_in[8];
    const float* b2     = (const float*)d_in[9];
    const float* Wm1    = (const float*)d_in[10];
    const float* bm1    = (const float*)d_in[11];
    const float* Wm2    = (const float*)d_in[12];
    const float* bm2    = (const float*)d_in[13];

    int N = in_sizes[0] / F_IN;
    int E = in_sizes[1] / 2;
    int Etot = E + N;

    char* ws = (char*)d_ws;
    size_t pos = 0;
    auto alloc = [&](size_t bytes) -> void* {
        void* p = ws + pos;
        pos = (pos + bytes + 255) & ~(size_t)255;
        return p;
    };
    _Float16* h16 = (_Float16*)alloc((size_t)N * HDIM * 2);
    _Float16* f16 = (_Float16*)alloc((size_t)N * HDIM * 2);
    float* as_buf = (float*)alloc((size_t)N * 4);
    float* ad_buf = (float*)alloc((size_t)N * 4);
    int*   deg    = (int*)alloc((size_t)((N + 3) & ~3) * 4);
    int*   offs   = (int*)alloc((size_t)(N + 1) * 4);
    int*   csr    = (int*)alloc((size_t)Etot * 4);
    int*   bsums  = (int*)alloc(256 * 4);
    _Float16* p1 = (_Float16*)alloc(65536 * 2);
    _Float16* p2 = (_Float16*)alloc(32768 * 2);
    _Float16* p3 = (_Float16*)alloc(32768 * 2);

    int eb = (Etot + 255) / 256;
    int nb = (N + SCAN_CHUNK - 1) / SCAN_CHUNK;
    int n4 = (N + 3) / 4;

    zero_kernel<<<(n4 + 255) / 256, 256, 0, stream>>>((int4*)deg, n4);
    count_kernel<<<eb, 256, 0, stream>>>(ei, E, N, deg);
    scan_reduce_kernel<<<nb, 256, 0, stream>>>(deg, N, bsums);
    scan_bsums_kernel<<<1, 256, 0, stream>>>(bsums, nb, offs, N);
    scan_down_kernel<<<nb, 256, 0, stream>>>(deg, N, bsums, offs);
    scatter_kernel<<<eb, 256, 0, stream>>>(ei, E, N, offs, deg, csr);

    pack_b_kernel<<<128, 64, 0, stream>>>(W1, W2, Wm1, p1, p2, p3);

    int gemm_blocks = (N + 31) / 32;
    int wave_blocks = (N + 3) / 4;

    // layer 1: h1 = x @ W1 (fused alphas); aggregate + relu
    gemm_mfma_kernel<0, 8, 0><<<gemm_blocks, 128, 0, stream>>>(x, p1, h16, N, nullptr, 0,
                                                               a_src1, a_dst1, as_buf, ad_buf,
                                                               nullptr, nullptr, nullptr);
    aggregate_kernel<<<wave_blocks, 256, 0, stream>>>(h16, as_buf, ad_buf, offs, csr, b1, f16, N, 1);

    // layer 2: h2 = f1 @ W2 (fused alphas); aggregate (no relu)
    gemm_mfma_kernel<1, 4, 0><<<gemm_blocks, 128, 0, stream>>>(f16, p2, h16, N, nullptr, 0,
                                                               a_src2, a_dst2, as_buf, ad_buf,
                                                               nullptr, nullptr, nullptr);
    aggregate_kernel<<<wave_blocks, 256, 0, stream>>>(h16, as_buf, ad_buf, offs, csr, b2, f16, N, 0);

    // MLP fused: z = relu(f2 @ Wm1 + bm1); out = sigmoid(z @ Wm2 + bm2)
    gemm_mfma_kernel<1, 4, 1><<<gemm_blocks, 128, 0, stream>>>(f16, p3, h16, N, bm1, 1,
                                                               nullptr, nullptr, nullptr, nullptr,
                                                               Wm2, bm2, (float*)d_out);
}

// Round 21
// 205.734 us; speedup vs baseline: 1.0373x; 1.0373x over previous
//
#include <hip/hip_runtime.h>
#include <math.h>

#define F_IN 256
#define HDIM 128
#define NCLS 20
#define NEG_SLOPE 0.2f
#define SCAN_CHUNK 1024

typedef float f32x4 __attribute__((ext_vector_type(4)));
typedef _Float16 f16x2 __attribute__((ext_vector_type(2)));
typedef _Float16 f16x4 __attribute__((ext_vector_type(4)));
typedef _Float16 f16x8 __attribute__((ext_vector_type(8)));

static __device__ __forceinline__ float lrelu(float x) { return x > 0.f ? x : NEG_SLOPE * x; }

// ---------------- fast zero ----------------
__global__ __launch_bounds__(256) void zero_kernel(int4* __restrict__ p, int n4) {
    int i = blockIdx.x * blockDim.x + threadIdx.x;
    if (i < n4) p[i] = make_int4(0, 0, 0, 0);
}

// ---------------- CSR build ----------------
__global__ void count_kernel(const int* __restrict__ ei, int E, int N, int* __restrict__ deg) {
    int e = blockIdx.x * blockDim.x + threadIdx.x;
    int Etot = E + N;
    if (e >= Etot) return;
    int d = (e < E) ? ei[E + e] : (e - E);
    atomicAdd(&deg[d], 1);
}

__global__ __launch_bounds__(256) void scan_reduce_kernel(const int* __restrict__ deg, int n,
                                                          int* __restrict__ bsums) {
    int base = blockIdx.x * SCAN_CHUNK + threadIdx.x * 4;
    int s = 0;
    if (base + 3 < n) {
        int4 v = *reinterpret_cast<const int4*>(&deg[base]);
        s = v.x + v.y + v.z + v.w;
    } else {
#pragma unroll
        for (int j = 0; j < 4; ++j) if (base + j < n) s += deg[base + j];
    }
#pragma unroll
    for (int o = 32; o > 0; o >>= 1) s += __shfl_down(s, o);
    __shared__ int ws[4];
    int lane = threadIdx.x & 63, w = threadIdx.x >> 6;
    if (lane == 0) ws[w] = s;
    __syncthreads();
    if (threadIdx.x == 0) bsums[blockIdx.x] = ws[0] + ws[1] + ws[2] + ws[3];
}

__global__ __launch_bounds__(256) void scan_bsums_kernel(int* __restrict__ bsums, int nb,
                                                         int* __restrict__ off, int n) {
    __shared__ int sh[256];
    int tid = threadIdx.x;
    int v = (tid < nb) ? bsums[tid] : 0;
    sh[tid] = v;
    __syncthreads();
    for (int d = 1; d < 256; d <<= 1) {
        int t = (tid >= d) ? sh[tid - d] : 0;
        __syncthreads();
        sh[tid] += t;
        __syncthreads();
    }
    if (tid < nb) bsums[tid] = sh[tid] - v;
    if (tid == 255) off[n] = sh[255];
}

__global__ __launch_bounds__(256) void scan_down_kernel(const int* __restrict__ deg, int n,
                                                        const int* __restrict__ bpre,
                                                        int* __restrict__ off) {
    int base = blockIdx.x * SCAN_CHUNK + threadIdx.x * 4;
    int v0 = 0, v1 = 0, v2 = 0, v3 = 0;
    if (base + 3 < n) {
        int4 t = *reinterpret_cast<const int4*>(&deg[base]);
        v0 = t.x; v1 = t.y; v2 = t.z; v3 = t.w;
    } else {
        if (base + 0 < n) v0 = deg[base + 0];
        if (base + 1 < n) v1 = deg[base + 1];
        if (base + 2 < n) v2 = deg[base + 2];
        if (base + 3 < n) v3 = deg[base + 3];
    }
    int tsum = v0 + v1 + v2 + v3;
    int lane = threadIdx.x & 63, w = threadIdx.x >> 6;
    int inc = tsum;
#pragma unroll
    for (int o = 1; o < 64; o <<= 1) {
        int t = __shfl_up(inc, o);
        if (lane >= o) inc += t;
    }
    int texc = inc - tsum;
    __shared__ int wsum[4];
    if (lane == 63) wsum[w] = inc;
    __syncthreads();
    int wpre = 0;
    for (int i = 0; i < w; ++i) wpre += wsum[i];
    int p = bpre[blockIdx.x] + wpre + texc;
    if (base + 3 < n) {
        int4 o4;
        o4.x = p; o4.y = p + v0; o4.z = p + v0 + v1; o4.w = p + v0 + v1 + v2;
        *reinterpret_cast<int4*>(&off[base]) = o4;
    } else {
        int run = p;
        if (base + 0 < n) { off[base + 0] = run; run += v0; }
        if (base + 1 < n) { off[base + 1] = run; run += v1; }
        if (base + 2 < n) { off[base + 2] = run; run += v2; }
        if (base + 3 < n) { off[base + 3] = run; }
    }
}

// scatter uses deg as a COUNTDOWN cursor (deg dead after scan).
__global__ void scatter_kernel(const int* __restrict__ ei, int E, int N,
                               const int* __restrict__ off, int* __restrict__ deg,
                               int* __restrict__ csr_src) {
    int e = blockIdx.x * blockDim.x + threadIdx.x;
    int Etot = E + N;
    if (e >= Etot) return;
    int s, d;
    if (e < E) { s = ei[e]; d = ei[E + e]; } else { s = d = e - E; }
    int pos = off[d] + atomicSub(&deg[d], 1) - 1;
    csr_src[pos] = s;
}

// ---------------- pack weights into MFMA B-fragment order (fp16 hi|lo interleaved) ----------------
__global__ __launch_bounds__(64) void pack_b_kernel(const float* __restrict__ W1,
                                                    const float* __restrict__ W2,
                                                    const float* __restrict__ Wm1,
                                                    _Float16* __restrict__ p1,
                                                    _Float16* __restrict__ p2,
                                                    _Float16* __restrict__ p3) {
    int t = blockIdx.x;
    int lane = threadIdx.x;
    const float* B; _Float16* out; int r;
    if (t < 64)      { B = W1;  out = p1; r = t; }
    else if (t < 96) { B = W2;  out = p2; r = t - 64; }
    else             { B = Wm1; out = p3; r = t - 96; }
    int ks = r >> 3, cf = r & 7;
    int c  = cf * 16 + (lane & 15);
    int k0 = ks * 32 + (lane >> 4) * 8;
    size_t base = ((size_t)r * 64 + lane) * 16;
#pragma unroll
    for (int i = 0; i < 8; ++i) {
        float v = B[(size_t)(k0 + i) * 128 + c];
        _Float16 h = (_Float16)v;
        out[base + i]     = h;
        out[base + 8 + i] = (_Float16)(v - (float)h);
    }
}

// ---------------- MFMA GEMM: C[M,128](fp16) = A[M,K] @ Bpacked[K,128] (+bias, act) ----------------
// r19 BEST-MEASURED (205.9us): block = 32 rows / 2 waves; wave = 32 rows x 64 cols;
// depth-2 ping-pong, compiler-scheduled. Failed alternatives (keep for the record):
// r10 8-wave/32x32 (-ILP), r16 split-K (+LDS/occupancy loss), r17/r18 register hoist
// (+pin) — regalloc sinks it, r20 whole-K LDS staging (stage+barrier+ds latency wash).
// Fused alpha epilogue (a_src != null); fused MLP head (FUSE_HEAD, gemm3 only).
template <int AFMT, int KSTEPS, int FUSE_HEAD>
__global__ __launch_bounds__(128) void gemm_mfma_kernel(
        const void* __restrict__ Aptr, const _Float16* __restrict__ Bp,
        _Float16* __restrict__ C, int M,
        const float* __restrict__ bias, int act,
        const float* __restrict__ a_src, const float* __restrict__ a_dst,
        float* __restrict__ as_out, float* __restrict__ ad_out,
        const float* __restrict__ Wh, const float* __restrict__ bh2,
        float* __restrict__ outp) {
    constexpr int K = KSTEPS * 32;
    __shared__ float sal[2][2][32];                                // alpha partials [as/ad][wc][row]
    __shared__ float zs[FUSE_HEAD ? 32 : 1][FUSE_HEAD ? 132 : 1];  // z tile (head)
    __shared__ float Wt[FUSE_HEAD ? 20 : 1][FUSE_HEAD ? 132 : 1];  // Wm2^T (head)
    __shared__ float bb[FUSE_HEAD ? 20 : 1];

    int tid = threadIdx.x;
    int lane = tid & 63;
    int wc = tid >> 6;                 // 0..1 (column half)
    int bm = blockIdx.x * 32;
    int l15 = lane & 15, l4 = lane >> 4;
    int row0 = bm + l15;
    int koff = l4 * 8;

    if constexpr (FUSE_HEAD) {
        for (int i = tid; i < HDIM * NCLS; i += 128) Wt[i % NCLS][i / NCLS] = Wh[i];
        if (tid < NCLS) bb[tid] = bh2[tid];
    }

    const float*    A32 = (const float*)Aptr;
    const _Float16* A16 = (const _Float16*)Aptr;
    bool ok0 = row0 < M, ok1 = (row0 + 16) < M;
    const f16x8 zf = {0, 0, 0, 0, 0, 0, 0, 0};

    f32x4 acc[2][4];
#pragma unroll
    for (int m = 0; m < 2; ++m)
#pragma unroll
        for (int j = 0; j < 4; ++j) acc[m][j] = (f32x4){0.f, 0.f, 0.f, 0.f};

    auto loadA = [&](int ks, f16x8 a[2]) {
        int kb = ks * 32 + koff;
#pragma unroll
        for (int m = 0; m < 2; ++m) {
            int rr = row0 + m * 16;
            bool ok = m ? ok1 : ok0;
            if (AFMT == 0) {
                if (ok) {
                    const float* p = &A32[(size_t)rr * K + kb];
                    float4 u = *reinterpret_cast<const float4*>(p);
                    float4 w = *reinterpret_cast<const float4*>(p + 4);
                    f16x8 t;
                    t[0] = (_Float16)u.x; t[1] = (_Float16)u.y;
                    t[2] = (_Float16)u.z; t[3] = (_Float16)u.w;
                    t[4] = (_Float16)w.x; t[5] = (_Float16)w.y;
                    t[6] = (_Float16)w.z; t[7] = (_Float16)w.w;
                    a[m] = t;
                } else a[m] = zf;
            } else {
                a[m] = ok ? *reinterpret_cast<const f16x8*>(&A16[(size_t)rr * K + kb]) : zf;
            }
        }
    };
    auto loadB = [&](int ks, f16x8 bh[4], f16x8 bl[4]) {
#pragma unroll
        for (int j = 0; j < 4; ++j) {
            int cf = wc * 4 + j;
            const _Float16* p = Bp + (((size_t)ks * 8 + cf) * 64 + lane) * 16;
            bh[j] = *reinterpret_cast<const f16x8*>(p);
            bl[j] = *reinterpret_cast<const f16x8*>(p + 8);
        }
    };

    f16x8 a0[2], a1[2], bh0[4], bh1[4], bl0[4], bl1[4];
    loadA(0, a0); loadB(0, bh0, bl0);
#pragma unroll
    for (int ks = 0; ks < KSTEPS; ks += 2) {
        loadA(ks + 1, a1); loadB(ks + 1, bh1, bl1);
#pragma unroll
        for (int j = 0; j < 4; ++j) {
            acc[0][j] = __builtin_amdgcn_mfma_f32_16x16x32_f16(a0[0], bh0[j], acc[0][j], 0, 0, 0);
            acc[1][j] = __builtin_amdgcn_mfma_f32_16x16x32_f16(a0[1], bh0[j], acc[1][j], 0, 0, 0);
            acc[0][j] = __builtin_amdgcn_mfma_f32_16x16x32_f16(a0[0], bl0[j], acc[0][j], 0, 0, 0);
            acc[1][j] = __builtin_amdgcn_mfma_f32_16x16x32_f16(a0[1], bl0[j], acc[1][j], 0, 0, 0);
        }
        if (ks + 2 < KSTEPS) { loadA(ks + 2, a0); loadB(ks + 2, bh0, bl0); }
#pragma unroll
        for (int j = 0; j < 4; ++j) {
            acc[0][j] = __builtin_amdgcn_mfma_f32_16x16x32_f16(a1[0], bh1[j], acc[0][j], 0, 0, 0);
            acc[1][j] = __builtin_amdgcn_mfma_f32_16x16x32_f16(a1[1], bh1[j], acc[1][j], 0, 0, 0);
            acc[0][j] = __builtin_amdgcn_mfma_f32_16x16x32_f16(a1[0], bl1[j], acc[0][j], 0, 0, 0);
            acc[1][j] = __builtin_amdgcn_mfma_f32_16x16x32_f16(a1[1], bl1[j], acc[1][j], 0, 0, 0);
        }
    }

    // epilogue: C/zs store (+ fused alpha partials)
    float ps[2][4], pd[2][4];
#pragma unroll
    for (int m = 0; m < 2; ++m)
#pragma unroll
        for (int reg = 0; reg < 4; ++reg) { ps[m][reg] = 0.f; pd[m][reg] = 0.f; }

#pragma unroll
    for (int j = 0; j < 4; ++j) {
        int col = wc * 64 + j * 16 + l15;
        float bi = bias ? bias[col] : 0.f;
        float asc = a_src ? a_src[col] : 0.f;
        float adc = a_src ? a_dst[col] : 0.f;
#pragma unroll
        for (int m = 0; m < 2; ++m) {
#pragma unroll
            for (int reg = 0; reg < 4; ++reg) {
                int rloc = m * 16 + l4 * 4 + reg;
                int rr = bm + rloc;
                float v = acc[m][j][reg] + bi;
                if (act) v = fmaxf(v, 0.f);
                if constexpr (FUSE_HEAD) {
                    zs[rloc][col] = v;
                } else {
                    if (rr < M) C[(size_t)rr * 128 + col] = (_Float16)v;
                }
                ps[m][reg] = fmaf(v, asc, ps[m][reg]);
                pd[m][reg] = fmaf(v, adc, pd[m][reg]);
            }
        }
    }

    if (a_src) {
#pragma unroll
        for (int o = 1; o < 16; o <<= 1) {
#pragma unroll
            for (int m = 0; m < 2; ++m)
#pragma unroll
                for (int reg = 0; reg < 4; ++reg) {
                    ps[m][reg] += __shfl_xor(ps[m][reg], o);
                    pd[m][reg] += __shfl_xor(pd[m][reg], o);
                }
        }
        if (l15 == 0) {
#pragma unroll
            for (int m = 0; m < 2; ++m)
#pragma unroll
                for (int reg = 0; reg < 4; ++reg) {
                    int rloc = m * 16 + l4 * 4 + reg;
                    sal[0][wc][rloc] = ps[m][reg];
                    sal[1][wc][rloc] = pd[m][reg];
                }
        }
        __syncthreads();
        if (tid < 32) {
            int rr = bm + tid;
            if (rr < M) {
                as_out[rr] = sal[0][0][tid] + sal[0][1][tid];
                ad_out[rr] = sal[1][0][tid] + sal[1][1][tid];
            }
        }
    }

    if constexpr (FUSE_HEAD) {
        __syncthreads();
        for (int idx = tid; idx < 32 * NCLS; idx += 128) {
            int r = idx / NCLS, c = idx % NCLS;
            int rr = bm + r;
            if (rr >= M) continue;
            float s = bb[c];
#pragma unroll
            for (int k = 0; k < HDIM; k += 4) {
                float4 z4 = *reinterpret_cast<const float4*>(&zs[r][k]);
                float4 w4 = *reinterpret_cast<const float4*>(&Wt[c][k]);
                s = fmaf(z4.x, w4.x, s);
                s = fmaf(z4.y, w4.y, s);
                s = fmaf(z4.z, w4.z, s);
                s = fmaf(z4.w, w4.w, s);
            }
            outp[(size_t)rr * NCLS + c] = 1.f / (1.f + __expf(-s));
        }
    }
}

// ---------------- attention aggregation: one wave per dst node (fp16 gather) ----------------
// Phase A: 64 edges in parallel -> e, denom; stash (src,e) in LDS.
// Phase B: 4 edges in flight (eslot = lane>>4), l15 owns 8 dims via one f16x8 load.
__global__ __launch_bounds__(256) void aggregate_kernel(const _Float16* __restrict__ h,
                                 const float* __restrict__ asrc, const float* __restrict__ adst,
                                 const int* __restrict__ off, const int* __restrict__ csr_src,
                                 const float* __restrict__ bias,
                                 _Float16* __restrict__ out,
                                 int N, int do_relu) {
    __shared__ float2 sm[4][64];
    int wslot = threadIdx.x >> 6;
    int wave = blockIdx.x * 4 + wslot;
    int lane = threadIdx.x & 63;
    if (wave >= N) return;
    int o0 = off[wave], o1 = off[wave + 1];
    float ad = adst[wave];
    int l15 = lane & 15;
    int eslot = lane >> 4;

    float denom = 0.f;
    float acc[8];
#pragma unroll
    for (int i = 0; i < 8; ++i) acc[i] = 0.f;

    for (int base = o0; base < o1; base += 64) {
        int cnt = o1 - base; if (cnt > 64) cnt = 64;
        float e = 0.f; int s = 0;
        if (lane < cnt) {
            s = csr_src[base + lane];
            e = __expf(lrelu(asrc[s] + ad));
        }
        float t = e;
#pragma unroll
        for (int o = 32; o > 0; o >>= 1) t += __shfl_xor(t, o);
        denom += t;
        sm[wslot][lane] = make_float2(__int_as_float(s), e);
        for (int j = eslot; j < cnt; j += 4) {
            float2 se = sm[wslot][j];
            int s0 = __float_as_int(se.x);
            f16x8 hv = *reinterpret_cast<const f16x8*>(&h[(size_t)s0 * HDIM + 8 * l15]);
#pragma unroll
            for (int i = 0; i < 8; ++i) acc[i] = fmaf(se.y, (float)hv[i], acc[i]);
        }
    }

#pragma unroll
    for (int i = 0; i < 8; ++i) {
        acc[i] += __shfl_xor(acc[i], 16);
        acc[i] += __shfl_xor(acc[i], 32);
    }

    if (lane < 16) {
        float inv = 1.f / denom;
        float4 b0 = *reinterpret_cast<const float4*>(&bias[8 * l15]);
        float4 b1 = *reinterpret_cast<const float4*>(&bias[8 * l15 + 4]);
        float bv[8] = {b0.x, b0.y, b0.z, b0.w, b1.x, b1.y, b1.z, b1.w};
        f16x8 o8;
#pragma unroll
        for (int i = 0; i < 8; ++i) {
            float v = acc[i] * inv + bv[i];
            if (do_relu) v = fmaxf(v, 0.f);
            o8[i] = (_Float16)v;
        }
        *reinterpret_cast<f16x8*>(&out[(size_t)wave * HDIM + 8 * l15]) = o8;
    }
}

extern "C" void kernel_launch(void* const* d_in, const int* in_sizes, int n_in,
                              void* d_out, int out_size, void* d_ws, size_t ws_size,
                              hipStream_t stream) {
    const float* x      = (const float*)d_in[0];
    const int*   ei     = (const int*)d_in[1];
    const float* W1     = (const float*)d_in[2];
    const float* a_src1 = (const float*)d_in[3];
    const float* a_dst1 = (const float*)d_in[4];
    const float* b1     = (const float*)d_in[5];
    const float* W2     = (const float*)d_in[6];
    const float* a_src2 = (const float*)d_in[7];
    const float* a_dst2 = (const float*)d_in[8];
    const float* b2     = (const float*)d_in[9];
    const float* Wm1    = (const float*)d_in[10];
    const float* bm1    = (const float*)d_in[11];
    const float* Wm2    = (const float*)d_in[12];
    const float* bm2    = (const float*)d_in[13];

    int N = in_sizes[0] / F_IN;
    int E = in_sizes[1] / 2;
    int Etot = E + N;

    char* ws = (char*)d_ws;
    size_t pos = 0;
    auto alloc = [&](size_t bytes) -> void* {
        void* p = ws + pos;
        pos = (pos + bytes + 255) & ~(size_t)255;
        return p;
    };
    _Float16* h16 = (_Float16*)alloc((size_t)N * HDIM * 2);
    _Float16* f16 = (_Float16*)alloc((size_t)N * HDIM * 2);
    float* as_buf = (float*)alloc((size_t)N * 4);
    float* ad_buf = (float*)alloc((size_t)N * 4);
    int*   deg    = (int*)alloc((size_t)((N + 3) & ~3) * 4);
    int*   offs   = (int*)alloc((size_t)(N + 1) * 4);
    int*   csr    = (int*)alloc((size_t)Etot * 4);
    int*   bsums  = (int*)alloc(256 * 4);
    _Float16* p1 = (_Float16*)alloc(65536 * 2);
    _Float16* p2 = (_Float16*)alloc(32768 * 2);
    _Float16* p3 = (_Float16*)alloc(32768 * 2);

    int eb = (Etot + 255) / 256;
    int nb = (N + SCAN_CHUNK - 1) / SCAN_CHUNK;
    int n4 = (N + 3) / 4;

    zero_kernel<<<(n4 + 255) / 256, 256, 0, stream>>>((int4*)deg, n4);
    count_kernel<<<eb, 256, 0, stream>>>(ei, E, N, deg);
    scan_reduce_kernel<<<nb, 256, 0, stream>>>(deg, N, bsums);
    scan_bsums_kernel<<<1, 256, 0, stream>>>(bsums, nb, offs, N);
    scan_down_kernel<<<nb, 256, 0, stream>>>(deg, N, bsums, offs);
    scatter_kernel<<<eb, 256, 0, stream>>>(ei, E, N, offs, deg, csr);

    pack_b_kernel<<<128, 64, 0, stream>>>(W1, W2, Wm1, p1, p2, p3);

    int gemm_blocks = (N + 31) / 32;
    int wave_blocks = (N + 3) / 4;

    // layer 1: h1 = x @ W1 (fused alphas); aggregate + relu
    gemm_mfma_kernel<0, 8, 0><<<gemm_blocks, 128, 0, stream>>>(x, p1, h16, N, nullptr, 0,
                                                               a_src1, a_dst1, as_buf, ad_buf,
                                                               nullptr, nullptr, nullptr);
    aggregate_kernel<<<wave_blocks, 256, 0, stream>>>(h16, as_buf, ad_buf, offs, csr, b1, f16, N, 1);

    // layer 2: h2 = f1 @ W2 (fused alphas); aggregate (no relu)
    gemm_mfma_kernel<1, 4, 0><<<gemm_blocks, 128, 0, stream>>>(f16, p2, h16, N, nullptr, 0,
                                                               a_src2, a_dst2, as_buf, ad_buf,
                                                               nullptr, nullptr, nullptr);
    aggregate_kernel<<<wave_blocks, 256, 0, stream>>>(h16, as_buf, ad_buf, offs, csr, b2, f16, N, 0);

    // MLP fused: z = relu(f2 @ Wm1 + bm1); out = sigmoid(z @ Wm2 + bm2)
    gemm_mfma_kernel<1, 4, 1><<<gemm_blocks, 128, 0, stream>>>(f16, p3, h16, N, bm1, 1,
                                                               nullptr, nullptr, nullptr, nullptr,
                                                               Wm2, bm2, (float*)d_out);
}

// Round 22
// 204.307 us; speedup vs baseline: 1.0445x; 1.0070x over previous
//
#include <hip/hip_runtime.h>
#include <math.h>

#define F_IN 256
#define HDIM 128
#define NCLS 20
#define NEG_SLOPE 0.2f
#define SCAN_CHUNK 1024

typedef float f32x4 __attribute__((ext_vector_type(4)));
typedef _Float16 f16x2 __attribute__((ext_vector_type(2)));
typedef _Float16 f16x4 __attribute__((ext_vector_type(4)));
typedef _Float16 f16x8 __attribute__((ext_vector_type(8)));

static __device__ __forceinline__ float lrelu(float x) { return x > 0.f ? x : NEG_SLOPE * x; }

// ---------------- CSR build ----------------
__global__ void count_kernel(const int* __restrict__ ei, int E, int N, int* __restrict__ deg) {
    int e = blockIdx.x * blockDim.x + threadIdx.x;
    int Etot = E + N;
    if (e >= Etot) return;
    int d = (e < E) ? ei[E + e] : (e - E);
    atomicAdd(&deg[d], 1);
}

__global__ __launch_bounds__(256) void scan_reduce_kernel(const int* __restrict__ deg, int n,
                                                          int* __restrict__ bsums) {
    int base = blockIdx.x * SCAN_CHUNK + threadIdx.x * 4;
    int s = 0;
    if (base + 3 < n) {
        int4 v = *reinterpret_cast<const int4*>(&deg[base]);
        s = v.x + v.y + v.z + v.w;
    } else {
#pragma unroll
        for (int j = 0; j < 4; ++j) if (base + j < n) s += deg[base + j];
    }
#pragma unroll
    for (int o = 32; o > 0; o >>= 1) s += __shfl_down(s, o);
    __shared__ int ws[4];
    int lane = threadIdx.x & 63, w = threadIdx.x >> 6;
    if (lane == 0) ws[w] = s;
    __syncthreads();
    if (threadIdx.x == 0) bsums[blockIdx.x] = ws[0] + ws[1] + ws[2] + ws[3];
}

__global__ __launch_bounds__(256) void scan_bsums_kernel(int* __restrict__ bsums, int nb,
                                                         int* __restrict__ off, int n) {
    __shared__ int sh[256];
    int tid = threadIdx.x;
    int v = (tid < nb) ? bsums[tid] : 0;
    sh[tid] = v;
    __syncthreads();
    for (int d = 1; d < 256; d <<= 1) {
        int t = (tid >= d) ? sh[tid - d] : 0;
        __syncthreads();
        sh[tid] += t;
        __syncthreads();
    }
    if (tid < nb) bsums[tid] = sh[tid] - v;
    if (tid == 255) off[n] = sh[255];
}

__global__ __launch_bounds__(256) void scan_down_kernel(const int* __restrict__ deg, int n,
                                                        const int* __restrict__ bpre,
                                                        int* __restrict__ off) {
    int base = blockIdx.x * SCAN_CHUNK + threadIdx.x * 4;
    int v0 = 0, v1 = 0, v2 = 0, v3 = 0;
    if (base + 3 < n) {
        int4 t = *reinterpret_cast<const int4*>(&deg[base]);
        v0 = t.x; v1 = t.y; v2 = t.z; v3 = t.w;
    } else {
        if (base + 0 < n) v0 = deg[base + 0];
        if (base + 1 < n) v1 = deg[base + 1];
        if (base + 2 < n) v2 = deg[base + 2];
        if (base + 3 < n) v3 = deg[base + 3];
    }
    int tsum = v0 + v1 + v2 + v3;
    int lane = threadIdx.x & 63, w = threadIdx.x >> 6;
    int inc = tsum;
#pragma unroll
    for (int o = 1; o < 64; o <<= 1) {
        int t = __shfl_up(inc, o);
        if (lane >= o) inc += t;
    }
    int texc = inc - tsum;
    __shared__ int wsum[4];
    if (lane == 63) wsum[w] = inc;
    __syncthreads();
    int wpre = 0;
    for (int i = 0; i < w; ++i) wpre += wsum[i];
    int p = bpre[blockIdx.x] + wpre + texc;
    if (base + 3 < n) {
        int4 o4;
        o4.x = p; o4.y = p + v0; o4.z = p + v0 + v1; o4.w = p + v0 + v1 + v2;
        *reinterpret_cast<int4*>(&off[base]) = o4;
    } else {
        int run = p;
        if (base + 0 < n) { off[base + 0] = run; run += v0; }
        if (base + 1 < n) { off[base + 1] = run; run += v1; }
        if (base + 2 < n) { off[base + 2] = run; run += v2; }
        if (base + 3 < n) { off[base + 3] = run; }
    }
}

// scatter uses deg as a COUNTDOWN cursor (deg dead after scan).
__global__ void scatter_kernel(const int* __restrict__ ei, int E, int N,
                               const int* __restrict__ off, int* __restrict__ deg,
                               int* __restrict__ csr_src) {
    int e = blockIdx.x * blockDim.x + threadIdx.x;
    int Etot = E + N;
    if (e >= Etot) return;
    int s, d;
    if (e < E) { s = ei[e]; d = ei[E + e]; } else { s = d = e - E; }
    int pos = off[d] + atomicSub(&deg[d], 1) - 1;
    csr_src[pos] = s;
}

// ---------------- prep: pack weights (blocks 0..31) + zero deg (blocks 32+) ----------------
// pack layout: out[((ks*8+cf)*64 + lane)*16 + i] = hi|lo fp16 of B[ks*32+(lane>>4)*8+i][cf*16+(lane&15)]
__global__ __launch_bounds__(256) void prep_kernel(const float* __restrict__ W1,
                                                   const float* __restrict__ W2,
                                                   const float* __restrict__ Wm1,
                                                   _Float16* __restrict__ p1,
                                                   _Float16* __restrict__ p2,
                                                   _Float16* __restrict__ p3,
                                                   int4* __restrict__ zp, int n4) {
    if (blockIdx.x < 32) {
        int t = blockIdx.x * 4 + (threadIdx.x >> 6);   // 0..127
        int lane = threadIdx.x & 63;
        const float* B; _Float16* out; int r;
        if (t < 64)      { B = W1;  out = p1; r = t; }
        else if (t < 96) { B = W2;  out = p2; r = t - 64; }
        else             { B = Wm1; out = p3; r = t - 96; }
        int ks = r >> 3, cf = r & 7;
        int c  = cf * 16 + (lane & 15);
        int k0 = ks * 32 + (lane >> 4) * 8;
        size_t base = ((size_t)r * 64 + lane) * 16;
#pragma unroll
        for (int i = 0; i < 8; ++i) {
            float v = B[(size_t)(k0 + i) * 128 + c];
            _Float16 h = (_Float16)v;
            out[base + i]     = h;
            out[base + 8 + i] = (_Float16)(v - (float)h);
        }
    } else {
        int i = (blockIdx.x - 32) * 256 + threadIdx.x;
        if (i < n4) zp[i] = make_int4(0, 0, 0, 0);
    }
}

// ---------------- MFMA GEMM: C[M,128](fp16) = A[M,K] @ Bpacked[K,128] (+bias, act) ----------------
// r19 BEST-MEASURED: block = 32 rows / 2 waves; wave = 32 rows x 64 cols;
// depth-2 ping-pong, compiler-scheduled. Failed alternatives: r10 8-wave (-ILP),
// r16 split-K, r17/r18 register hoist (regalloc sinks it), r20 LDS staging (wash).
// Fused alpha epilogue (a_src != null); fused MLP head (FUSE_HEAD, gemm3 only).
template <int AFMT, int KSTEPS, int FUSE_HEAD>
__global__ __launch_bounds__(128) void gemm_mfma_kernel(
        const void* __restrict__ Aptr, const _Float16* __restrict__ Bp,
        _Float16* __restrict__ C, int M,
        const float* __restrict__ bias, int act,
        const float* __restrict__ a_src, const float* __restrict__ a_dst,
        float* __restrict__ as_out, float* __restrict__ ad_out,
        const float* __restrict__ Wh, const float* __restrict__ bh2,
        float* __restrict__ outp) {
    constexpr int K = KSTEPS * 32;
    __shared__ float sal[2][2][32];                                // alpha partials [as/ad][wc][row]
    __shared__ float zs[FUSE_HEAD ? 32 : 1][FUSE_HEAD ? 132 : 1];  // z tile (head)
    __shared__ float Wt[FUSE_HEAD ? 20 : 1][FUSE_HEAD ? 132 : 1];  // Wm2^T (head)
    __shared__ float bb[FUSE_HEAD ? 20 : 1];

    int tid = threadIdx.x;
    int lane = tid & 63;
    int wc = tid >> 6;                 // 0..1 (column half)
    int bm = blockIdx.x * 32;
    int l15 = lane & 15, l4 = lane >> 4;
    int row0 = bm + l15;
    int koff = l4 * 8;

    if constexpr (FUSE_HEAD) {
        for (int i = tid; i < HDIM * NCLS; i += 128) Wt[i % NCLS][i / NCLS] = Wh[i];
        if (tid < NCLS) bb[tid] = bh2[tid];
    }

    const float*    A32 = (const float*)Aptr;
    const _Float16* A16 = (const _Float16*)Aptr;
    bool ok0 = row0 < M, ok1 = (row0 + 16) < M;
    const f16x8 zf = {0, 0, 0, 0, 0, 0, 0, 0};

    f32x4 acc[2][4];
#pragma unroll
    for (int m = 0; m < 2; ++m)
#pragma unroll
        for (int j = 0; j < 4; ++j) acc[m][j] = (f32x4){0.f, 0.f, 0.f, 0.f};

    auto loadA = [&](int ks, f16x8 a[2]) {
        int kb = ks * 32 + koff;
#pragma unroll
        for (int m = 0; m < 2; ++m) {
            int rr = row0 + m * 16;
            bool ok = m ? ok1 : ok0;
            if (AFMT == 0) {
                if (ok) {
                    const float* p = &A32[(size_t)rr * K + kb];
                    float4 u = *reinterpret_cast<const float4*>(p);
                    float4 w = *reinterpret_cast<const float4*>(p + 4);
                    f16x8 t;
                    t[0] = (_Float16)u.x; t[1] = (_Float16)u.y;
                    t[2] = (_Float16)u.z; t[3] = (_Float16)u.w;
                    t[4] = (_Float16)w.x; t[5] = (_Float16)w.y;
                    t[6] = (_Float16)w.z; t[7] = (_Float16)w.w;
                    a[m] = t;
                } else a[m] = zf;
            } else {
                a[m] = ok ? *reinterpret_cast<const f16x8*>(&A16[(size_t)rr * K + kb]) : zf;
            }
        }
    };
    auto loadB = [&](int ks, f16x8 bh[4], f16x8 bl[4]) {
#pragma unroll
        for (int j = 0; j < 4; ++j) {
            int cf = wc * 4 + j;
            const _Float16* p = Bp + (((size_t)ks * 8 + cf) * 64 + lane) * 16;
            bh[j] = *reinterpret_cast<const f16x8*>(p);
            bl[j] = *reinterpret_cast<const f16x8*>(p + 8);
        }
    };

    f16x8 a0[2], a1[2], bh0[4], bh1[4], bl0[4], bl1[4];
    loadA(0, a0); loadB(0, bh0, bl0);
#pragma unroll
    for (int ks = 0; ks < KSTEPS; ks += 2) {
        loadA(ks + 1, a1); loadB(ks + 1, bh1, bl1);
#pragma unroll
        for (int j = 0; j < 4; ++j) {
            acc[0][j] = __builtin_amdgcn_mfma_f32_16x16x32_f16(a0[0], bh0[j], acc[0][j], 0, 0, 0);
            acc[1][j] = __builtin_amdgcn_mfma_f32_16x16x32_f16(a0[1], bh0[j], acc[1][j], 0, 0, 0);
            acc[0][j] = __builtin_amdgcn_mfma_f32_16x16x32_f16(a0[0], bl0[j], acc[0][j], 0, 0, 0);
            acc[1][j] = __builtin_amdgcn_mfma_f32_16x16x32_f16(a0[1], bl0[j], acc[1][j], 0, 0, 0);
        }
        if (ks + 2 < KSTEPS) { loadA(ks + 2, a0); loadB(ks + 2, bh0, bl0); }
#pragma unroll
        for (int j = 0; j < 4; ++j) {
            acc[0][j] = __builtin_amdgcn_mfma_f32_16x16x32_f16(a1[0], bh1[j], acc[0][j], 0, 0, 0);
            acc[1][j] = __builtin_amdgcn_mfma_f32_16x16x32_f16(a1[1], bh1[j], acc[1][j], 0, 0, 0);
            acc[0][j] = __builtin_amdgcn_mfma_f32_16x16x32_f16(a1[0], bl1[j], acc[0][j], 0, 0, 0);
            acc[1][j] = __builtin_amdgcn_mfma_f32_16x16x32_f16(a1[1], bl1[j], acc[1][j], 0, 0, 0);
        }
    }

    // epilogue: C/zs store (+ fused alpha partials)
    float ps[2][4], pd[2][4];
#pragma unroll
    for (int m = 0; m < 2; ++m)
#pragma unroll
        for (int reg = 0; reg < 4; ++reg) { ps[m][reg] = 0.f; pd[m][reg] = 0.f; }

#pragma unroll
    for (int j = 0; j < 4; ++j) {
        int col = wc * 64 + j * 16 + l15;
        float bi = bias ? bias[col] : 0.f;
        float asc = a_src ? a_src[col] : 0.f;
        float adc = a_src ? a_dst[col] : 0.f;
#pragma unroll
        for (int m = 0; m < 2; ++m) {
#pragma unroll
            for (int reg = 0; reg < 4; ++reg) {
                int rloc = m * 16 + l4 * 4 + reg;
                int rr = bm + rloc;
                float v = acc[m][j][reg] + bi;
                if (act) v = fmaxf(v, 0.f);
                if constexpr (FUSE_HEAD) {
                    zs[rloc][col] = v;
                } else {
                    if (rr < M) C[(size_t)rr * 128 + col] = (_Float16)v;
                }
                ps[m][reg] = fmaf(v, asc, ps[m][reg]);
                pd[m][reg] = fmaf(v, adc, pd[m][reg]);
            }
        }
    }

    if (a_src) {
#pragma unroll
        for (int o = 1; o < 16; o <<= 1) {
#pragma unroll
            for (int m = 0; m < 2; ++m)
#pragma unroll
                for (int reg = 0; reg < 4; ++reg) {
                    ps[m][reg] += __shfl_xor(ps[m][reg], o);
                    pd[m][reg] += __shfl_xor(pd[m][reg], o);
                }
        }
        if (l15 == 0) {
#pragma unroll
            for (int m = 0; m < 2; ++m)
#pragma unroll
                for (int reg = 0; reg < 4; ++reg) {
                    int rloc = m * 16 + l4 * 4 + reg;
                    sal[0][wc][rloc] = ps[m][reg];
                    sal[1][wc][rloc] = pd[m][reg];
                }
        }
        __syncthreads();
        if (tid < 32) {
            int rr = bm + tid;
            if (rr < M) {
                as_out[rr] = sal[0][0][tid] + sal[0][1][tid];
                ad_out[rr] = sal[1][0][tid] + sal[1][1][tid];
            }
        }
    }

    if constexpr (FUSE_HEAD) {
        __syncthreads();
        for (int idx = tid; idx < 32 * NCLS; idx += 128) {
            int r = idx / NCLS, c = idx % NCLS;
            int rr = bm + r;
            if (rr >= M) continue;
            float s = bb[c];
#pragma unroll
            for (int k = 0; k < HDIM; k += 4) {
                float4 z4 = *reinterpret_cast<const float4*>(&zs[r][k]);
                float4 w4 = *reinterpret_cast<const float4*>(&Wt[c][k]);
                s = fmaf(z4.x, w4.x, s);
                s = fmaf(z4.y, w4.y, s);
                s = fmaf(z4.z, w4.z, s);
                s = fmaf(z4.w, w4.w, s);
            }
            outp[(size_t)rr * NCLS + c] = 1.f / (1.f + __expf(-s));
        }
    }
}

// ---------------- attention aggregation: one wave per dst node (fp16 gather) ----------------
// Phase A: 64 edges in parallel -> e, denom; stash (src,e) in LDS.
// Phase B: 8 gathers in flight (4 eslots x unroll-2, split accumulators) —
// gathers hit L3 (h16 = 12.8MB > 4MB/XCD L2), ~250cy each; deeper MLP hides more.
__global__ __launch_bounds__(256) void aggregate_kernel(const _Float16* __restrict__ h,
                                 const float* __restrict__ asrc, const float* __restrict__ adst,
                                 const int* __restrict__ off, const int* __restrict__ csr_src,
                                 const float* __restrict__ bias,
                                 _Float16* __restrict__ out,
                                 int N, int do_relu) {
    __shared__ float2 sm[4][64];
    int wslot = threadIdx.x >> 6;
    int wave = blockIdx.x * 4 + wslot;
    int lane = threadIdx.x & 63;
    if (wave >= N) return;
    int o0 = off[wave], o1 = off[wave + 1];
    float ad = adst[wave];
    int l15 = lane & 15;
    int eslot = lane >> 4;

    float denom = 0.f;
    float accA[8], accB[8];
#pragma unroll
    for (int i = 0; i < 8; ++i) { accA[i] = 0.f; accB[i] = 0.f; }

    for (int base = o0; base < o1; base += 64) {
        int cnt = o1 - base; if (cnt > 64) cnt = 64;
        float e = 0.f; int s = 0;
        if (lane < cnt) {
            s = csr_src[base + lane];
            e = __expf(lrelu(asrc[s] + ad));
        }
        float t = e;
#pragma unroll
        for (int o = 32; o > 0; o >>= 1) t += __shfl_xor(t, o);
        denom += t;
        sm[wslot][lane] = make_float2(__int_as_float(s), e);

        int j = eslot;
        for (; j + 4 < cnt; j += 8) {
            float2 s0 = sm[wslot][j];
            float2 s1 = sm[wslot][j + 4];
            int i0 = __float_as_int(s0.x);
            int i1 = __float_as_int(s1.x);
            f16x8 h0 = *reinterpret_cast<const f16x8*>(&h[(size_t)i0 * HDIM + 8 * l15]);
            f16x8 h1 = *reinterpret_cast<const f16x8*>(&h[(size_t)i1 * HDIM + 8 * l15]);
#pragma unroll
            for (int i = 0; i < 8; ++i) {
                accA[i] = fmaf(s0.y, (float)h0[i], accA[i]);
                accB[i] = fmaf(s1.y, (float)h1[i], accB[i]);
            }
        }
        if (j < cnt) {
            float2 s0 = sm[wslot][j];
            int i0 = __float_as_int(s0.x);
            f16x8 h0 = *reinterpret_cast<const f16x8*>(&h[(size_t)i0 * HDIM + 8 * l15]);
#pragma unroll
            for (int i = 0; i < 8; ++i) accA[i] = fmaf(s0.y, (float)h0[i], accA[i]);
        }
    }

#pragma unroll
    for (int i = 0; i < 8; ++i) {
        float a = accA[i] + accB[i];
        a += __shfl_xor(a, 16);
        a += __shfl_xor(a, 32);
        accA[i] = a;
    }

    if (lane < 16) {
        float inv = 1.f / denom;
        float4 b0 = *reinterpret_cast<const float4*>(&bias[8 * l15]);
        float4 b1 = *reinterpret_cast<const float4*>(&bias[8 * l15 + 4]);
        float bv[8] = {b0.x, b0.y, b0.z, b0.w, b1.x, b1.y, b1.z, b1.w};
        f16x8 o8;
#pragma unroll
        for (int i = 0; i < 8; ++i) {
            float v = accA[i] * inv + bv[i];
            if (do_relu) v = fmaxf(v, 0.f);
            o8[i] = (_Float16)v;
        }
        *reinterpret_cast<f16x8*>(&out[(size_t)wave * HDIM + 8 * l15]) = o8;
    }
}

extern "C" void kernel_launch(void* const* d_in, const int* in_sizes, int n_in,
                              void* d_out, int out_size, void* d_ws, size_t ws_size,
                              hipStream_t stream) {
    const float* x      = (const float*)d_in[0];
    const int*   ei     = (const int*)d_in[1];
    const float* W1     = (const float*)d_in[2];
    const float* a_src1 = (const float*)d_in[3];
    const float* a_dst1 = (const float*)d_in[4];
    const float* b1     = (const float*)d_in[5];
    const float* W2     = (const float*)d_in[6];
    const float* a_src2 = (const float*)d_in[7];
    const float* a_dst2 = (const float*)d_in[8];
    const float* b2     = (const float*)d_in[9];
    const float* Wm1    = (const float*)d_in[10];
    const float* bm1    = (const float*)d_in[11];
    const float* Wm2    = (const float*)d_in[12];
    const float* bm2    = (const float*)d_in[13];

    int N = in_sizes[0] / F_IN;
    int E = in_sizes[1] / 2;
    int Etot = E + N;

    char* ws = (char*)d_ws;
    size_t pos = 0;
    auto alloc = [&](size_t bytes) -> void* {
        void* p = ws + pos;
        pos = (pos + bytes + 255) & ~(size_t)255;
        return p;
    };
    _Float16* h16 = (_Float16*)alloc((size_t)N * HDIM * 2);
    _Float16* f16 = (_Float16*)alloc((size_t)N * HDIM * 2);
    float* as_buf = (float*)alloc((size_t)N * 4);
    float* ad_buf = (float*)alloc((size_t)N * 4);
    int*   deg    = (int*)alloc((size_t)((N + 3) & ~3) * 4);
    int*   offs   = (int*)alloc((size_t)(N + 1) * 4);
    int*   csr    = (int*)alloc((size_t)Etot * 4);
    int*   bsums  = (int*)alloc(256 * 4);
    _Float16* p1 = (_Float16*)alloc(65536 * 2);
    _Float16* p2 = (_Float16*)alloc(32768 * 2);
    _Float16* p3 = (_Float16*)alloc(32768 * 2);

    int eb = (Etot + 255) / 256;
    int nb = (N + SCAN_CHUNK - 1) / SCAN_CHUNK;
    int n4 = (N + 3) / 4;
    int zb = (n4 + 255) / 256;

    prep_kernel<<<32 + zb, 256, 0, stream>>>(W1, W2, Wm1, p1, p2, p3, (int4*)deg, n4);
    count_kernel<<<eb, 256, 0, stream>>>(ei, E, N, deg);
    scan_reduce_kernel<<<nb, 256, 0, stream>>>(deg, N, bsums);
    scan_bsums_kernel<<<1, 256, 0, stream>>>(bsums, nb, offs, N);
    scan_down_kernel<<<nb, 256, 0, stream>>>(deg, N, bsums, offs);
    scatter_kernel<<<eb, 256, 0, stream>>>(ei, E, N, offs, deg, csr);

    int gemm_blocks = (N + 31) / 32;
    int wave_blocks = (N + 3) / 4;

    // layer 1: h1 = x @ W1 (fused alphas); aggregate + relu
    gemm_mfma_kernel<0, 8, 0><<<gemm_blocks, 128, 0, stream>>>(x, p1, h16, N, nullptr, 0,
                                                               a_src1, a_dst1, as_buf, ad_buf,
                                                               nullptr, nullptr, nullptr);
    aggregate_kernel<<<wave_blocks, 256, 0, stream>>>(h16, as_buf, ad_buf, offs, csr, b1, f16, N, 1);

    // layer 2: h2 = f1 @ W2 (fused alphas); aggregate (no relu)
    gemm_mfma_kernel<1, 4, 0><<<gemm_blocks, 128, 0, stream>>>(f16, p2, h16, N, nullptr, 0,
                                                               a_src2, a_dst2, as_buf, ad_buf,
                                                               nullptr, nullptr, nullptr);
    aggregate_kernel<<<wave_blocks, 256, 0, stream>>>(h16, as_buf, ad_buf, offs, csr, b2, f16, N, 0);

    // MLP fused: z = relu(f2 @ Wm1 + bm1); out = sigmoid(z @ Wm2 + bm2)
    gemm_mfma_kernel<1, 4, 1><<<gemm_blocks, 128, 0, stream>>>(f16, p3, h16, N, bm1, 1,
                                                               nullptr, nullptr, nullptr, nullptr,
                                                               Wm2, bm2, (float*)d_out);
}